// Round 2
// baseline (291.119 us; speedup 1.0000x reference)
//
#include <hip/hip_runtime.h>

#define T_ 4
#define C_ 3
#define H_ 128
#define W_ 128
#define PS_ 5
#define K_ 14
#define WS_ 15
#define SW_ 7
#define PW_ 2
#define RAD_ 9
#define HP_ 146          // H_ + 2*RAD_
#define NOFF 225
#define SD_ 142          // S domain (H_ + WS_ - 1)
#define CHUNK 45         // offsets per chunk (3 oy rows)
#define NCHUNK 5
#define STRIPH 16
#define HROWS 20         // STRIPH + PS_ - 1
#define HCOLS 132        // W_ + PS_ - 1

typedef unsigned int u32;

// ---------------- Kernel 1: per-(t,c) means ----------------
__global__ __launch_bounds__(256) void means_kernel(const float* __restrict__ noisy,
                                                    float* __restrict__ means) {
    int tc = blockIdx.x;
    const float* img = noisy + (size_t)tc * (H_*W_);
    float s = 0.f;
    for (int e = threadIdx.x; e < H_*W_; e += 256) s += img[e];
    #pragma unroll
    for (int off = 32; off; off >>= 1) s += __shfl_down(s, off, 64);
    __shared__ float red[4];
    int lane = threadIdx.x & 63, wv = threadIdx.x >> 6;
    if (lane == 0) red[wv] = s;
    __syncthreads();
    if (threadIdx.x == 0) {
        float tot = red[0] + red[1] + red[2] + red[3];
        means[tc] = tot / (float)(H_*W_) * (1.0f/127.5f) - 1.0f;
    }
}

// ---------------- Kernel 2: normalize + mean-subtract + reflect pad ----------------
__global__ __launch_bounds__(256) void pad_kernel(const float* __restrict__ noisy,
                                                  const float* __restrict__ means,
                                                  float* __restrict__ P) {
    int total = T_*C_*HP_*HP_;
    int e = blockIdx.x * 256 + threadIdx.x;
    if (e >= total) return;
    int x  = e % HP_;
    int y  = (e / HP_) % HP_;
    int tc = e / (HP_*HP_);
    int ry = y - RAD_; if (ry < 0) ry = -ry; else if (ry > H_-1) ry = 2*(H_-1) - ry;
    int rx = x - RAD_; if (rx < 0) rx = -rx; else if (rx > W_-1) rx = 2*(W_-1) - rx;
    P[e] = noisy[(size_t)tc*(H_*W_) + ry*W_ + rx] * (1.0f/127.5f) - 1.0f - means[tc];
}

// ---------------- Kernel 3: column sums of sum_c P^2 ----------------
__global__ __launch_bounds__(256) void colq_kernel(const float* __restrict__ P,
                                                   float* __restrict__ colq) {
    int total = T_*SD_*HP_;
    int e = blockIdx.x * 256 + threadIdx.x;
    if (e >= total) return;
    int x = e % HP_;
    int y = (e / HP_) % SD_;
    int t = e / (HP_*SD_);
    const float* Pt = P + (size_t)t*(C_*HP_*HP_);
    float s = 0.f;
    #pragma unroll
    for (int u = 0; u < PS_; ++u) {
        int r = (y+u)*HP_ + x;
        float a = Pt[r], b = Pt[HP_*HP_ + r], c = Pt[2*HP_*HP_ + r];
        s += a*a + b*b + c*c;
    }
    colq[e] = s;
}

// ---------------- Kernel 4: S = row sums of colq (box5 of sum_c P^2) ----------------
__global__ __launch_bounds__(256) void s_kernel(const float* __restrict__ colq,
                                                float* __restrict__ S) {
    int total = T_*SD_*SD_;
    int e = blockIdx.x * 256 + threadIdx.x;
    if (e >= total) return;
    int x = e % SD_;
    int y = (e / SD_) % SD_;
    int t = e / (SD_*SD_);
    const float* cq = colq + ((size_t)t*SD_ + y)*HP_ + x;
    S[e] = cq[0] + cq[1] + cq[2] + cq[3] + cq[4];
}

// ---------------- Kernel 5: D for one offset chunk ----------------
// D(x,o) (shifted by -Sbase(x), order/softmax-invariant) = S[o+x] - 2*box5(h_o)(x)
__global__ __launch_bounds__(256) void dcomp_kernel(const float* __restrict__ P,
                                                    const float* __restrict__ S,
                                                    float* __restrict__ D,
                                                    int obase) {
    __shared__ __align__(16) float h[HROWS*HCOLS];
    __shared__ __align__(16) float cs[STRIPH*HCOLS];
    const int o  = obase + blockIdx.x;
    const int oy = o / WS_, ox = o % WS_;
    const int r0 = blockIdx.y * STRIPH;
    const int t  = blockIdx.z;
    const float* Pt = P + (size_t)t*(C_*HP_*HP_);
    const int tid = threadIdx.x;

    // phase 1: product image h over (HROWS x HCOLS)
    for (int e = tid; e < HROWS*HCOLS; e += 256) {
        int yr = e / HCOLS, yc = e % HCOLS;
        int bi = (SW_ + r0 + yr)*HP_ + SW_ + yc;
        int si = (oy  + r0 + yr)*HP_ + ox  + yc;
        h[e] = Pt[bi]*Pt[si]
             + Pt[HP_*HP_ + bi]*Pt[HP_*HP_ + si]
             + Pt[2*HP_*HP_ + bi]*Pt[2*HP_*HP_ + si];
    }
    __syncthreads();

    // phase 2: column sums cs[r][c] = sum_p h[r+p][c]  (float4 groups)
    for (int g = tid; g < STRIPH*(HCOLS/4); g += 256) {
        int r = g / (HCOLS/4), c4 = (g % (HCOLS/4))*4;
        float4 acc = *(const float4*)&h[r*HCOLS + c4];
        #pragma unroll
        for (int p = 1; p < PS_; ++p) {
            float4 v = *(const float4*)&h[(r+p)*HCOLS + c4];
            acc.x += v.x; acc.y += v.y; acc.z += v.z; acc.w += v.w;
        }
        *(float4*)&cs[r*HCOLS + c4] = acc;
    }
    __syncthreads();

    // phase 3: row sums + combine with S, write D
    const float* St = S + (size_t)t*SD_*SD_;
    for (int g = tid; g < STRIPH*(W_/4); g += 256) {
        int r = g / (W_/4), c4 = (g % (W_/4))*4;
        float4 a = *(const float4*)&cs[r*HCOLS + c4];
        float4 b = *(const float4*)&cs[r*HCOLS + c4 + 4];
        float e0=a.x, e1=a.y, e2=a.z, e3=a.w, e4=b.x, e5=b.y, e6=b.z;
        int srow = (oy + r0 + r)*SD_ + ox + c4;
        float4 dv;
        float m1234 = e1+e2+e3+e4;
        dv.x = St[srow+0] - 2.f*(e0+m1234);
        dv.y = St[srow+1] - 2.f*(m1234+e5);
        float m2345 = e2+e3+e4+e5;
        dv.z = St[srow+2] - 2.f*(m2345+e6);
        dv.w = St[srow+3] - 2.f*(e3+e4+e5+e6+b.w);
        *(float4*)&D[(((size_t)blockIdx.x*T_ + t)*H_ + (r0+r))*W_ + c4] = dv;
    }
}

// ---------------- Kernel 6: chunked top-K scan (+ final softmax) ----------------
__global__ __launch_bounds__(256) void scan_kernel(const float* __restrict__ D,
                                                   const float* __restrict__ sigma,
                                                   float* __restrict__ dstate,
                                                   u32* __restrict__ istate,
                                                   float* __restrict__ wts,
                                                   uint4* __restrict__ idxpack,
                                                   int obase) {
    int px = blockIdx.x*256 + threadIdx.x;   // 65536 total
    const bool first = (obase == 0);
    const bool last  = (obase + CHUNK == NOFF);

    float dbest[K_]; int ibest[K_];
    if (first) {
        #pragma unroll
        for (int k = 0; k < K_; ++k) { dbest[k] = 1e30f; ibest[k] = 0; }
    } else {
        const float4* ds = (const float4*)&dstate[(size_t)px*16];
        float4 v0 = ds[0], v1 = ds[1], v2 = ds[2], v3 = ds[3];
        dbest[0]=v0.x; dbest[1]=v0.y; dbest[2]=v0.z; dbest[3]=v0.w;
        dbest[4]=v1.x; dbest[5]=v1.y; dbest[6]=v1.z; dbest[7]=v1.w;
        dbest[8]=v2.x; dbest[9]=v2.y; dbest[10]=v2.z; dbest[11]=v2.w;
        dbest[12]=v3.x; dbest[13]=v3.y;
        uint4 iv = ((const uint4*)istate)[px];
        u32 w0=iv.x, w1=iv.y, w2=iv.z, w3=iv.w;
        ibest[0]=w0&255; ibest[1]=(w0>>8)&255; ibest[2]=(w0>>16)&255; ibest[3]=(int)(w0>>24);
        ibest[4]=w1&255; ibest[5]=(w1>>8)&255; ibest[6]=(w1>>16)&255; ibest[7]=(int)(w1>>24);
        ibest[8]=w2&255; ibest[9]=(w2>>8)&255; ibest[10]=(w2>>16)&255; ibest[11]=(int)(w2>>24);
        ibest[12]=w3&255; ibest[13]=(w3>>8)&255;
    }

    for (int ol = 0; ol < CHUNK; ++ol) {
        float d = D[(size_t)ol*(T_*H_*W_) + px];
        int o = obase + ol;
        if (d < dbest[K_-1]) {
            dbest[K_-1] = d; ibest[K_-1] = o;
            #pragma unroll
            for (int k = K_-1; k > 0; --k) {
                if (dbest[k] < dbest[k-1]) {
                    float td = dbest[k]; dbest[k] = dbest[k-1]; dbest[k-1] = td;
                    int   ti = ibest[k]; ibest[k] = ibest[k-1]; ibest[k-1] = ti;
                }
            }
        }
    }

    if (!last) {
        float4* ds = (float4*)&dstate[(size_t)px*16];
        ds[0] = make_float4(dbest[0],dbest[1],dbest[2],dbest[3]);
        ds[1] = make_float4(dbest[4],dbest[5],dbest[6],dbest[7]);
        ds[2] = make_float4(dbest[8],dbest[9],dbest[10],dbest[11]);
        ds[3] = make_float4(dbest[12],dbest[13],0.f,0.f);
        uint4 iv;
        iv.x = (u32)ibest[0] | ((u32)ibest[1]<<8) | ((u32)ibest[2]<<16) | ((u32)ibest[3]<<24);
        iv.y = (u32)ibest[4] | ((u32)ibest[5]<<8) | ((u32)ibest[6]<<16) | ((u32)ibest[7]<<24);
        iv.z = (u32)ibest[8] | ((u32)ibest[9]<<8) | ((u32)ibest[10]<<16) | ((u32)ibest[11]<<24);
        iv.w = (u32)ibest[12] | ((u32)ibest[13]<<8);
        ((uint4*)istate)[px] = iv;
    } else {
        float sig = sigma[0] * (1.0f/255.0f) * 2.0f;
        float denom = 2.0f * (float)(C_*PS_*PS_) * (sig*sig) + 1e-8f;
        float m = dbest[0];
        float w[K_]; float sum = 0.f;
        #pragma unroll
        for (int k = 0; k < K_; ++k) { w[k] = expf(-(dbest[k]-m)/denom); sum += w[k]; }
        float inv = 1.0f / sum;
        float4* wv = (float4*)&wts[(size_t)px*16];
        wv[0] = make_float4(w[0]*inv,  w[1]*inv,  w[2]*inv,  w[3]*inv);
        wv[1] = make_float4(w[4]*inv,  w[5]*inv,  w[6]*inv,  w[7]*inv);
        wv[2] = make_float4(w[8]*inv,  w[9]*inv,  w[10]*inv, w[11]*inv);
        wv[3] = make_float4(w[12]*inv, w[13]*inv, 0.f, 0.f);
        uint4 iv;
        iv.x = (u32)ibest[0] | ((u32)ibest[1]<<8) | ((u32)ibest[2]<<16) | ((u32)ibest[3]<<24);
        iv.y = (u32)ibest[4] | ((u32)ibest[5]<<8) | ((u32)ibest[6]<<16) | ((u32)ibest[7]<<24);
        iv.z = (u32)ibest[8] | ((u32)ibest[9]<<8) | ((u32)ibest[10]<<16) | ((u32)ibest[11]<<24);
        iv.w = (u32)ibest[12] | ((u32)ibest[13]<<8);
        idxpack[px] = iv;
    }
}

// ---------------- Kernel 7: gather-aggregate + final affine ----------------
__global__ __launch_bounds__(256) void agg_kernel(const float* __restrict__ P,
                                                  const float* __restrict__ wts,
                                                  const uint4* __restrict__ idxpack,
                                                  const float* __restrict__ means,
                                                  float* __restrict__ out) {
    int gid = blockIdx.x * 256 + threadIdx.x;
    if (gid >= T_*H_*W_) return;
    int jo = gid % W_;
    int io = (gid / W_) % H_;
    int t  = gid / (H_*W_);
    int y = io + PW_, x = jo + PW_;
    const float* Pt = P + (size_t)t * (C_*HP_*HP_);

    float s0 = 0.f, s1 = 0.f, s2 = 0.f;
    int count = 0;
    #pragma unroll
    for (int a = 0; a < PS_; ++a) {
        int qi = y - a; if (qi < 0 || qi >= H_) continue;
        #pragma unroll
        for (int b = 0; b < PS_; ++b) {
            int qj = x - b; if (qj < 0 || qj >= W_) continue;
            ++count;
            size_t q = ((size_t)t*H_ + qi)*W_ + qj;
            const float4* wv = (const float4*)&wts[q*16];
            float4 wa = wv[0], wb = wv[1], wc = wv[2], wd = wv[3];
            uint4 ip = idxpack[q];
            #define ACC(wval, obits) { \
                u32 o_ = (obits); \
                u32 oy_ = o_ / 15u; u32 ox_ = o_ - oy_*15u; \
                int pr = (y + (int)oy_)*HP_ + x + (int)ox_; \
                float w_ = (wval); \
                s0 += w_ * Pt[pr]; \
                s1 += w_ * Pt[HP_*HP_ + pr]; \
                s2 += w_ * Pt[2*HP_*HP_ + pr]; }
            ACC(wa.x, ip.x & 255u);       ACC(wa.y, (ip.x>>8) & 255u);
            ACC(wa.z, (ip.x>>16) & 255u); ACC(wa.w, ip.x>>24);
            ACC(wb.x, ip.y & 255u);       ACC(wb.y, (ip.y>>8) & 255u);
            ACC(wb.z, (ip.y>>16) & 255u); ACC(wb.w, ip.y>>24);
            ACC(wc.x, ip.z & 255u);       ACC(wc.y, (ip.z>>8) & 255u);
            ACC(wc.z, (ip.z>>16) & 255u); ACC(wc.w, ip.z>>24);
            ACC(wd.x, ip.w & 255u);       ACC(wd.y, (ip.w>>8) & 255u);
            #undef ACC
        }
    }
    float invc = 1.0f / ((float)count + 1e-10f);
    float m0 = means[t*3+0], m1 = means[t*3+1], m2 = means[t*3+2];
    size_t obase = (size_t)t*(C_*H_*W_) + (size_t)io*W_ + jo;
    out[obase]             = 127.5f * (s0*invc + m0 + 1.0f);
    out[obase +   H_*W_]   = 127.5f * (s1*invc + m1 + 1.0f);
    out[obase + 2*(H_*W_)] = 127.5f * (s2*invc + m2 + 1.0f);
}

extern "C" void kernel_launch(void* const* d_in, const int* in_sizes, int n_in,
                              void* d_out, int out_size, void* d_ws, size_t ws_size,
                              hipStream_t stream) {
    const float* noisy = (const float*)d_in[0];
    const float* sigma = (const float*)d_in[1];
    float* out = (float*)d_out;
    float* ws  = (float*)d_ws;

    // ws layout (float offsets):
    float* means   = ws;                        // [0,16)
    float* P       = ws + 16;                   // 255792
    float* colq    = ws + 255808;               // 82928
    float* S       = ws + 338736;               // 80656
    float* wts     = ws + 419392;               // 65536*16
    uint4* idxpack = (uint4*)(ws + 1467968);    // 65536*4 u32
    float* dstate  = ws + 1730112;              // 65536*16
    u32*   istate  = (u32*)(ws + 2778688);      // 65536*4 u32
    float* D       = ws + 3040832;              // 45*4*128*128 = 2949120
    // total = 5,989,952 floats = ~24 MB

    hipLaunchKernelGGL(means_kernel, dim3(T_*C_), dim3(256), 0, stream, noisy, means);

    int padN = T_*C_*HP_*HP_;
    hipLaunchKernelGGL(pad_kernel, dim3((padN + 255)/256), dim3(256), 0, stream,
                       noisy, means, P);

    int cqN = T_*SD_*HP_;
    hipLaunchKernelGGL(colq_kernel, dim3((cqN + 255)/256), dim3(256), 0, stream, P, colq);

    int sN = T_*SD_*SD_;
    hipLaunchKernelGGL(s_kernel, dim3((sN + 255)/256), dim3(256), 0, stream, colq, S);

    for (int chunk = 0; chunk < NCHUNK; ++chunk) {
        int obase = chunk * CHUNK;
        hipLaunchKernelGGL(dcomp_kernel, dim3(CHUNK, H_/STRIPH, T_), dim3(256), 0, stream,
                           P, S, D, obase);
        hipLaunchKernelGGL(scan_kernel, dim3(T_*H_*W_/256), dim3(256), 0, stream,
                           D, sigma, dstate, istate, wts, idxpack, obase);
    }

    hipLaunchKernelGGL(agg_kernel, dim3((T_*H_*W_ + 255)/256), dim3(256), 0, stream,
                       P, wts, idxpack, means, out);
}

// Round 3
// 187.921 us; speedup vs baseline: 1.5492x; 1.5492x over previous
//
#include <hip/hip_runtime.h>

#define T_ 4
#define C_ 3
#define H_ 128
#define W_ 128
#define PS_ 5
#define K_ 14
#define WS_ 15
#define SW_ 7
#define PW_ 2
#define RAD_ 9
#define HP_ 146          // H_ + 2*RAD_
#define NOFF 225
#define SD_ 142          // S domain

#define TILE 16
#define SPR 34           // sP rows/cols (pixels)
#define SPS 36           // sP row stride (pixels; each pixel is a float4)
#define HS 24            // h row stride (floats), h is 20x20
#define CSS 24           // cs row stride, cs is 16x20
#define SSR 30           // sS rows/cols
#define SSS 33           // sS row stride
#define NPIX (T_*H_*W_)  // 65536

typedef unsigned int u32;

// ---------------- Kernel 1: per-(t,c) means ----------------
__global__ __launch_bounds__(256) void means_kernel(const float* __restrict__ noisy,
                                                    float* __restrict__ means) {
    int tc = blockIdx.x;
    const float* img = noisy + (size_t)tc * (H_*W_);
    float s = 0.f;
    for (int e = threadIdx.x; e < H_*W_; e += 256) s += img[e];
    #pragma unroll
    for (int off = 32; off; off >>= 1) s += __shfl_down(s, off, 64);
    __shared__ float red[4];
    int lane = threadIdx.x & 63, wv = threadIdx.x >> 6;
    if (lane == 0) red[wv] = s;
    __syncthreads();
    if (threadIdx.x == 0) {
        float tot = red[0] + red[1] + red[2] + red[3];
        means[tc] = tot / (float)(H_*W_) * (1.0f/127.5f) - 1.0f;
    }
}

// ---------------- Kernel 2: normalize + mean-subtract + reflect pad, interleaved float4 ----------------
__global__ __launch_bounds__(256) void pad4_kernel(const float* __restrict__ noisy,
                                                   const float* __restrict__ means,
                                                   float4* __restrict__ P4) {
    int e = blockIdx.x * 256 + threadIdx.x;
    if (e >= T_*HP_*HP_) return;
    int x = e % HP_;
    int y = (e / HP_) % HP_;
    int t = e / (HP_*HP_);
    int ry = y - RAD_; if (ry < 0) ry = -ry; else if (ry > H_-1) ry = 2*(H_-1) - ry;
    int rx = x - RAD_; if (rx < 0) rx = -rx; else if (rx > W_-1) rx = 2*(W_-1) - rx;
    const float* nt = noisy + (size_t)t*(C_*H_*W_) + ry*W_ + rx;
    float4 v;
    v.x = nt[0]         * (1.0f/127.5f) - 1.0f - means[t*3+0];
    v.y = nt[H_*W_]     * (1.0f/127.5f) - 1.0f - means[t*3+1];
    v.z = nt[2*(H_*W_)] * (1.0f/127.5f) - 1.0f - means[t*3+2];
    v.w = 0.f;
    P4[e] = v;
}

// ---------------- Kernel 3: column sums of sum_c P^2 ----------------
__global__ __launch_bounds__(256) void colq_kernel(const float4* __restrict__ P4,
                                                   float* __restrict__ colq) {
    int e = blockIdx.x * 256 + threadIdx.x;
    if (e >= T_*SD_*HP_) return;
    int x = e % HP_;
    int y = (e / HP_) % SD_;
    int t = e / (HP_*SD_);
    const float4* Pt = P4 + (size_t)t*(HP_*HP_);
    float s = 0.f;
    #pragma unroll
    for (int u = 0; u < PS_; ++u) {
        float4 v = Pt[(y+u)*HP_ + x];
        s += v.x*v.x + v.y*v.y + v.z*v.z;
    }
    colq[e] = s;
}

// ---------------- Kernel 4: S = row sums of colq ----------------
__global__ __launch_bounds__(256) void s_kernel(const float* __restrict__ colq,
                                                float* __restrict__ S) {
    int e = blockIdx.x * 256 + threadIdx.x;
    if (e >= T_*SD_*SD_) return;
    int x = e % SD_;
    int y = (e / SD_) % SD_;
    int t = e / (SD_*SD_);
    const float* cq = colq + ((size_t)t*SD_ + y)*HP_ + x;
    S[e] = cq[0] + cq[1] + cq[2] + cq[3] + cq[4];
}

// ---------------- Kernel 5: fused distance + top-K over an offset half ----------------
// D(x,o) (shifted by pixel-constant, order/softmax-invariant) = S[o+x] - 2*box5(h_o)(x)
__global__ __launch_bounds__(256) void fused_topk(const float4* __restrict__ P4,
                                                  const float* __restrict__ S,
                                                  float* __restrict__ pd,
                                                  uint4* __restrict__ pidx) {
    __shared__ float4 sP[SPR*SPS];
    __shared__ float  h2[2][20*HS];
    __shared__ float  csb[TILE*CSS];
    __shared__ float  sS[SSR*SSS];

    const int tid = threadIdx.x;
    const int tx = tid & 15, ty = tid >> 4;
    const int z = blockIdx.z;                 // 0..7
    const int t = z >> 1, half = z & 1;
    const int i0 = blockIdx.y * TILE, j0 = blockIdx.x * TILE;
    const float4* Pt = P4 + (size_t)t * (HP_*HP_);
    const float*  St = S  + (size_t)t * (SD_*SD_);

    for (int e = tid; e < SPR*SPR; e += 256) {
        int r = e / SPR, c = e % SPR;
        sP[r*SPS + c] = Pt[(i0 + r)*HP_ + (j0 + c)];
    }
    for (int e = tid; e < SSR*SSR; e += 256) {
        int r = e / SSR, c = e % SSR;
        sS[r*SSS + c] = St[(i0 + r)*SD_ + (j0 + c)];
    }
    __syncthreads();

    // phase-A positions: e0 = tid, e1 = tid + 256 (valid when tid < 144); h domain 20x20
    const int a0r = tid / 20, a0c = tid % 20;
    const int a1r = (tid + 256) / 20, a1c = (tid + 256) % 20;
    const bool has1 = (tid < 144);
    const float4 b0 = sP[(a0r + SW_)*SPS + (a0c + SW_)];
    const float4 b1 = has1 ? sP[(a1r + SW_)*SPS + (a1c + SW_)] : make_float4(0,0,0,0);

    auto phA = [&](int o, float* hb) {
        int oy = o / 15, ox = o % 15;
        float4 sv = sP[(a0r + oy)*SPS + (a0c + ox)];
        hb[a0r*HS + a0c] = b0.x*sv.x + b0.y*sv.y + b0.z*sv.z;
        if (has1) {
            float4 sw = sP[(a1r + oy)*SPS + (a1c + ox)];
            hb[a1r*HS + a1c] = b1.x*sw.x + b1.y*sw.y + b1.z*sw.z;
        }
    };
    auto phB = [&](const float* hb) {
        for (int e = tid; e < 320; e += 256) {
            int r = e / 20, c = e % 20;
            const float* hr = hb + r*HS + c;
            csb[r*CSS + c] = hr[0] + hr[HS] + hr[2*HS] + hr[3*HS] + hr[4*HS];
        }
    };

    float dbest[K_]; int ibest[K_];
    #pragma unroll
    for (int k = 0; k < K_; ++k) { dbest[k] = 1e30f; ibest[k] = 0; }

    const int obeg = half ? 112 : 0;
    const int oend = half ? 225 : 112;

    phA(obeg, h2[0]);
    __syncthreads();
    phB(h2[0]);
    __syncthreads();

    for (int i = obeg; i < oend; ++i) {
        // phase C: row-sum of cs + combine with S + insert
        {
            int oy = i / 15, ox = i % 15;
            const float* cr = csb + ty*CSS + tx;
            float V = cr[0] + cr[1] + cr[2] + cr[3] + cr[4];
            float d = sS[(ty + oy)*SSS + (tx + ox)] - 2.f*V;
            if (d < dbest[K_-1]) {
                dbest[K_-1] = d; ibest[K_-1] = i;
                #pragma unroll
                for (int k = K_-1; k > 0; --k) {
                    if (dbest[k] < dbest[k-1]) {
                        float td = dbest[k]; dbest[k] = dbest[k-1]; dbest[k-1] = td;
                        int   ti = ibest[k]; ibest[k] = ibest[k-1]; ibest[k-1] = ti;
                    }
                }
            }
        }
        bool more = (i + 1 < oend);
        if (more) phA(i + 1, h2[(i + 1 - obeg) & 1]);
        __syncthreads();
        if (more) phB(h2[(i + 1 - obeg) & 1]);
        __syncthreads();
    }

    int px = ((t*H_ + i0 + ty)*W_ + j0 + tx);
    float4* pdp = (float4*)(pd + ((size_t)half*NPIX + px)*16);
    pdp[0] = make_float4(dbest[0], dbest[1], dbest[2], dbest[3]);
    pdp[1] = make_float4(dbest[4], dbest[5], dbest[6], dbest[7]);
    pdp[2] = make_float4(dbest[8], dbest[9], dbest[10], dbest[11]);
    pdp[3] = make_float4(dbest[12], dbest[13], 1e30f, 1e30f);
    uint4 iv;
    iv.x = (u32)ibest[0]  | ((u32)ibest[1]<<8)  | ((u32)ibest[2]<<16)  | ((u32)ibest[3]<<24);
    iv.y = (u32)ibest[4]  | ((u32)ibest[5]<<8)  | ((u32)ibest[6]<<16)  | ((u32)ibest[7]<<24);
    iv.z = (u32)ibest[8]  | ((u32)ibest[9]<<8)  | ((u32)ibest[10]<<16) | ((u32)ibest[11]<<24);
    iv.w = (u32)ibest[12] | ((u32)ibest[13]<<8);
    pidx[(size_t)half*NPIX + px] = iv;
}

// ---------------- Kernel 6: merge halves + softmax ----------------
__global__ __launch_bounds__(256) void merge_kernel(const float* __restrict__ pd,
                                                    const uint4* __restrict__ pidx,
                                                    const float* __restrict__ sigma,
                                                    float* __restrict__ wts,
                                                    uint4* __restrict__ idxpack) {
    int px = blockIdx.x*256 + threadIdx.x;

    const float4* p0 = (const float4*)(pd + (size_t)px*16);
    float4 a0 = p0[0], a1 = p0[1], a2 = p0[2], a3 = p0[3];
    float dbest[K_] = {a0.x,a0.y,a0.z,a0.w, a1.x,a1.y,a1.z,a1.w,
                       a2.x,a2.y,a2.z,a2.w, a3.x,a3.y};
    uint4 iva = pidx[px];
    int ibest[K_] = {(int)(iva.x&255),(int)((iva.x>>8)&255),(int)((iva.x>>16)&255),(int)(iva.x>>24),
                     (int)(iva.y&255),(int)((iva.y>>8)&255),(int)((iva.y>>16)&255),(int)(iva.y>>24),
                     (int)(iva.z&255),(int)((iva.z>>8)&255),(int)((iva.z>>16)&255),(int)(iva.z>>24),
                     (int)(iva.w&255),(int)((iva.w>>8)&255)};

    const float4* p1 = (const float4*)(pd + ((size_t)NPIX + px)*16);
    float4 c0 = p1[0], c1 = p1[1], c2 = p1[2], c3 = p1[3];
    float dc[K_] = {c0.x,c0.y,c0.z,c0.w, c1.x,c1.y,c1.z,c1.w,
                    c2.x,c2.y,c2.z,c2.w, c3.x,c3.y};
    uint4 ivb = pidx[NPIX + px];
    int ic[K_] = {(int)(ivb.x&255),(int)((ivb.x>>8)&255),(int)((ivb.x>>16)&255),(int)(ivb.x>>24),
                  (int)(ivb.y&255),(int)((ivb.y>>8)&255),(int)((ivb.y>>16)&255),(int)(ivb.y>>24),
                  (int)(ivb.z&255),(int)((ivb.z>>8)&255),(int)((ivb.z>>16)&255),(int)(ivb.z>>24),
                  (int)(ivb.w&255),(int)((ivb.w>>8)&255)};

    #pragma unroll
    for (int k = 0; k < K_; ++k) {
        float d = dc[k];
        if (d < dbest[K_-1]) {
            dbest[K_-1] = d; ibest[K_-1] = ic[k];
            #pragma unroll
            for (int j = K_-1; j > 0; --j) {
                if (dbest[j] < dbest[j-1]) {
                    float td = dbest[j]; dbest[j] = dbest[j-1]; dbest[j-1] = td;
                    int   ti = ibest[j]; ibest[j] = ibest[j-1]; ibest[j-1] = ti;
                }
            }
        }
    }

    float sig = sigma[0] * (1.0f/255.0f) * 2.0f;
    float denom = 2.0f * (float)(C_*PS_*PS_) * (sig*sig) + 1e-8f;
    float m = dbest[0];
    float w[K_]; float sum = 0.f;
    #pragma unroll
    for (int k = 0; k < K_; ++k) { w[k] = expf(-(dbest[k]-m)/denom); sum += w[k]; }
    float inv = 1.0f / sum;

    float4* wv = (float4*)(wts + (size_t)px*16);
    wv[0] = make_float4(w[0]*inv,  w[1]*inv,  w[2]*inv,  w[3]*inv);
    wv[1] = make_float4(w[4]*inv,  w[5]*inv,  w[6]*inv,  w[7]*inv);
    wv[2] = make_float4(w[8]*inv,  w[9]*inv,  w[10]*inv, w[11]*inv);
    wv[3] = make_float4(w[12]*inv, w[13]*inv, 0.f, 0.f);
    uint4 iv;
    iv.x = (u32)ibest[0]  | ((u32)ibest[1]<<8)  | ((u32)ibest[2]<<16)  | ((u32)ibest[3]<<24);
    iv.y = (u32)ibest[4]  | ((u32)ibest[5]<<8)  | ((u32)ibest[6]<<16)  | ((u32)ibest[7]<<24);
    iv.z = (u32)ibest[8]  | ((u32)ibest[9]<<8)  | ((u32)ibest[10]<<16) | ((u32)ibest[11]<<24);
    iv.w = (u32)ibest[12] | ((u32)ibest[13]<<8);
    idxpack[px] = iv;
}

// ---------------- Kernel 7: gather-aggregate, 4 threads/pixel ----------------
__global__ __launch_bounds__(256) void agg_kernel(const float4* __restrict__ P4,
                                                  const float* __restrict__ wts,
                                                  const uint4* __restrict__ idxpack,
                                                  const float* __restrict__ means,
                                                  float* __restrict__ out) {
    int gid = blockIdx.x * 256 + threadIdx.x;   // 4*NPIX threads
    int part = gid & 3;
    int px   = gid >> 2;
    int jo = px % W_;
    int io = (px / W_) % H_;
    int t  = px / (H_*W_);
    int y = io + PW_, x = jo + PW_;
    const float4* Pt = P4 + (size_t)t * (HP_*HP_);

    float s0 = 0.f, s1 = 0.f, s2 = 0.f, cnt = 0.f;
    #pragma unroll
    for (int ab = 0; ab < 25; ++ab) {
        if ((ab & 3) != part) continue;
        int a = ab / 5, b = ab % 5;
        int qi = y - a, qj = x - b;
        if (qi < 0 || qi >= H_ || qj < 0 || qj >= W_) continue;
        cnt += 1.f;
        size_t q = ((size_t)t*H_ + qi)*W_ + qj;
        const float4* wv = (const float4*)&wts[q*16];
        float4 wa = wv[0], wb = wv[1], wc = wv[2], wd = wv[3];
        uint4 ip = idxpack[q];
        #define ACC(wval, obits) { \
            u32 o_ = (obits); \
            u32 oy_ = o_ / 15u; u32 ox_ = o_ - oy_*15u; \
            float4 v_ = Pt[(y + (int)oy_)*HP_ + x + (int)ox_]; \
            float w_ = (wval); \
            s0 += w_ * v_.x; s1 += w_ * v_.y; s2 += w_ * v_.z; }
        ACC(wa.x, ip.x & 255u);       ACC(wa.y, (ip.x>>8) & 255u);
        ACC(wa.z, (ip.x>>16) & 255u); ACC(wa.w, ip.x>>24);
        ACC(wb.x, ip.y & 255u);       ACC(wb.y, (ip.y>>8) & 255u);
        ACC(wb.z, (ip.y>>16) & 255u); ACC(wb.w, ip.y>>24);
        ACC(wc.x, ip.z & 255u);       ACC(wc.y, (ip.z>>8) & 255u);
        ACC(wc.z, (ip.z>>16) & 255u); ACC(wc.w, ip.z>>24);
        ACC(wd.x, ip.w & 255u);       ACC(wd.y, (ip.w>>8) & 255u);
        #undef ACC
    }

    s0 += __shfl_xor(s0, 1, 64); s0 += __shfl_xor(s0, 2, 64);
    s1 += __shfl_xor(s1, 1, 64); s1 += __shfl_xor(s1, 2, 64);
    s2 += __shfl_xor(s2, 1, 64); s2 += __shfl_xor(s2, 2, 64);
    cnt += __shfl_xor(cnt, 1, 64); cnt += __shfl_xor(cnt, 2, 64);

    if (part == 0) {
        float invc = 1.0f / (cnt + 1e-10f);
        float m0 = means[t*3+0], m1 = means[t*3+1], m2 = means[t*3+2];
        size_t obase = (size_t)t*(C_*H_*W_) + (size_t)io*W_ + jo;
        out[obase]             = 127.5f * (s0*invc + m0 + 1.0f);
        out[obase +   H_*W_]   = 127.5f * (s1*invc + m1 + 1.0f);
        out[obase + 2*(H_*W_)] = 127.5f * (s2*invc + m2 + 1.0f);
    }
}

extern "C" void kernel_launch(void* const* d_in, const int* in_sizes, int n_in,
                              void* d_out, int out_size, void* d_ws, size_t ws_size,
                              hipStream_t stream) {
    const float* noisy = (const float*)d_in[0];
    const float* sigma = (const float*)d_in[1];
    float* out = (float*)d_out;
    float* ws  = (float*)d_ws;

    // ws layout (float offsets, all 16-float aligned):
    float*  means   = ws;                       // 16
    float4* P4      = (float4*)(ws + 16);       // T*HP*HP float4 = 341056 floats
    float*  colq    = ws + 16 + 341056;         // 82928 -> pad 82944
    float*  S       = ws + 16 + 341056 + 82944; // 80656 -> pad 80672
    float*  wts     = ws + 16 + 341056 + 82944 + 80672;            // 1048576
    uint4*  idxpack = (uint4*)(wts + 1048576);                     // 262144 floats
    float*  pd      = (float*)idxpack + 262144;                    // 2*NPIX*16 = 2097152
    uint4*  pidx    = (uint4*)(pd + 2097152);                      // 524288 floats
    // total ~4.44M floats ~ 17.8 MB

    hipLaunchKernelGGL(means_kernel, dim3(T_*C_), dim3(256), 0, stream, noisy, means);

    int padN = T_*HP_*HP_;
    hipLaunchKernelGGL(pad4_kernel, dim3((padN + 255)/256), dim3(256), 0, stream,
                       noisy, means, P4);

    int cqN = T_*SD_*HP_;
    hipLaunchKernelGGL(colq_kernel, dim3((cqN + 255)/256), dim3(256), 0, stream, P4, colq);

    int sN = T_*SD_*SD_;
    hipLaunchKernelGGL(s_kernel, dim3((sN + 255)/256), dim3(256), 0, stream, colq, S);

    hipLaunchKernelGGL(fused_topk, dim3(W_/TILE, H_/TILE, T_*2), dim3(256), 0, stream,
                       P4, S, pd, pidx);

    hipLaunchKernelGGL(merge_kernel, dim3(NPIX/256), dim3(256), 0, stream,
                       pd, pidx, sigma, wts, idxpack);

    hipLaunchKernelGGL(agg_kernel, dim3(4*NPIX/256), dim3(256), 0, stream,
                       P4, wts, idxpack, means, out);
}

// Round 5
// 106.003 us; speedup vs baseline: 2.7463x; 1.7728x over previous
//
#include <hip/hip_runtime.h>

#define T_ 4
#define C_ 3
#define H_ 128
#define W_ 128
#define PS_ 5
#define K_ 14
#define WS_ 15
#define SW_ 7
#define PW_ 2
#define RAD_ 9
#define HP_ 146          // H_ + 2*RAD_
#define NOFF 225
#define SD_ 142          // S domain

#define TILE 16
#define SPR 34           // sP rows/cols (pixels)
#define SPS 37           // sP row stride (float4s) - rotates banks
#define HS 24            // h row stride (floats), h is 20x20
#define CSS 24           // cs row stride, cs is 16x20
#define SSR 30           // sS rows/cols
#define SSS 33           // sS row stride
#define NPIX (T_*H_*W_)  // 65536
#define NQ 4

#define AT 8             // agg tile
#define APR 22           // staged P4 rows (AT + 14)
#define APS 23           // staged P4 stride (float4s)
#define AWR 12           // staged wts rows (AT + 4)
#define AWS 20           // staged wts stride per pixel (floats) - bank spread

typedef unsigned int u32;

// ---------------- Kernel 1: per-(t,c) means ----------------
__global__ __launch_bounds__(256) void means_kernel(const float* __restrict__ noisy,
                                                    float* __restrict__ means) {
    int tc = blockIdx.x;
    const float* img = noisy + (size_t)tc * (H_*W_);
    float s = 0.f;
    for (int e = threadIdx.x; e < H_*W_; e += 256) s += img[e];
    #pragma unroll
    for (int off = 32; off; off >>= 1) s += __shfl_down(s, off, 64);
    __shared__ float red[4];
    int lane = threadIdx.x & 63, wv = threadIdx.x >> 6;
    if (lane == 0) red[wv] = s;
    __syncthreads();
    if (threadIdx.x == 0) {
        float tot = red[0] + red[1] + red[2] + red[3];
        means[tc] = tot / (float)(H_*W_) * (1.0f/127.5f) - 1.0f;
    }
}

// ---------------- Kernel 2: normalize + mean-subtract + reflect pad, interleaved float4 ----------------
__global__ __launch_bounds__(256) void pad4_kernel(const float* __restrict__ noisy,
                                                   const float* __restrict__ means,
                                                   float4* __restrict__ P4) {
    int e = blockIdx.x * 256 + threadIdx.x;
    if (e >= T_*HP_*HP_) return;
    int x = e % HP_;
    int y = (e / HP_) % HP_;
    int t = e / (HP_*HP_);
    int ry = y - RAD_; if (ry < 0) ry = -ry; else if (ry > H_-1) ry = 2*(H_-1) - ry;
    int rx = x - RAD_; if (rx < 0) rx = -rx; else if (rx > W_-1) rx = 2*(W_-1) - rx;
    const float* nt = noisy + (size_t)t*(C_*H_*W_) + ry*W_ + rx;
    float4 v;
    v.x = nt[0]         * (1.0f/127.5f) - 1.0f - means[t*3+0];
    v.y = nt[H_*W_]     * (1.0f/127.5f) - 1.0f - means[t*3+1];
    v.z = nt[2*(H_*W_)] * (1.0f/127.5f) - 1.0f - means[t*3+2];
    v.w = 0.f;
    P4[e] = v;
}

// ---------------- Kernel 3: column sums of sum_c P^2 ----------------
__global__ __launch_bounds__(256) void colq_kernel(const float4* __restrict__ P4,
                                                   float* __restrict__ colq) {
    int e = blockIdx.x * 256 + threadIdx.x;
    if (e >= T_*SD_*HP_) return;
    int x = e % HP_;
    int y = (e / HP_) % SD_;
    int t = e / (HP_*SD_);
    const float4* Pt = P4 + (size_t)t*(HP_*HP_);
    float s = 0.f;
    #pragma unroll
    for (int u = 0; u < PS_; ++u) {
        float4 v = Pt[(y+u)*HP_ + x];
        s += v.x*v.x + v.y*v.y + v.z*v.z;
    }
    colq[e] = s;
}

// ---------------- Kernel 4: S = row sums of colq ----------------
__global__ __launch_bounds__(256) void s_kernel(const float* __restrict__ colq,
                                                float* __restrict__ S) {
    int e = blockIdx.x * 256 + threadIdx.x;
    if (e >= T_*SD_*SD_) return;
    int x = e % SD_;
    int y = (e / SD_) % SD_;
    int t = e / (SD_*SD_);
    const float* cq = colq + ((size_t)t*SD_ + y)*HP_ + x;
    S[e] = cq[0] + cq[1] + cq[2] + cq[3] + cq[4];
}

// ---------------- Kernel 5: fused distance + top-K over an offset quarter ----------------
// d_true(x,o) = S_base(x) + S[o+x] - 2*box5(h_o)(x)  (clamped >= 0)
// key = (bits(d) & 0xFFFFFF00) | o  -> uint order == (d, o) lexicographic
__global__ __launch_bounds__(256) void fused_topk(const float4* __restrict__ P4,
                                                  const float* __restrict__ S,
                                                  uint4* __restrict__ pkey) {
    __shared__ float4 sP[SPR*SPS];
    __shared__ float  h[4][20*HS];
    __shared__ float  cs[4][16*CSS];
    __shared__ float  sS[SSR*SSS];

    const int tid = threadIdx.x;
    const int tx = tid & 15, ty = tid >> 4;
    const int z = blockIdx.z;                 // 0..15
    const int t = z >> 2, q = z & 3;
    const int i0 = blockIdx.y * TILE, j0 = blockIdx.x * TILE;
    const float4* Pt = P4 + (size_t)t * (HP_*HP_);
    const float*  St = S  + (size_t)t * (SD_*SD_);

    for (int e = tid; e < SPR*SPR; e += 256) {
        int r = e / SPR, c = e % SPR;
        sP[r*SPS + c] = Pt[(i0 + r)*HP_ + (j0 + c)];
    }
    for (int e = tid; e < SSR*SSR; e += 256) {
        int r = e / SSR, c = e % SSR;
        sS[r*SSS + c] = St[(i0 + r)*SD_ + (j0 + c)];
    }
    __syncthreads();

    const int a0r = tid / 20, a0c = tid % 20;
    const int a1r = (tid + 256) / 20, a1c = (tid + 256) % 20;
    const bool has1 = (tid < 144);
    const float4 b0 = sP[(a0r + SW_)*SPS + (a0c + SW_)];
    const float4 b1 = has1 ? sP[(a1r + SW_)*SPS + (a1c + SW_)] : make_float4(0,0,0,0);
    const float Sbase = sS[(ty + SW_)*SSS + (tx + SW_)];

    // phase-B task for this thread: g = tid (always), g2 = tid+256 (tid<64)
    const int pb_b  = tid / 80;
    const int pb_r  = (tid - 80*pb_b) & 15;
    const int pb_cg = (tid - 80*pb_b) >> 4;
    const int g2    = tid + 256;
    const int pb2_b  = g2 / 80;                 // always 3
    const int pb2_r  = (g2 - 80*pb2_b) & 15;
    const int pb2_cg = (g2 - 80*pb2_b) >> 4;

    u32 kb[K_];
    #pragma unroll
    for (int k = 0; k < K_; ++k) kb[k] = 0xFFFFFFFFu;

    const int obeg = (q == 0) ? 0 : 57 + (q-1)*56;
    const int oend = obeg + ((q == 0) ? 57 : 56);

    for (int ob = obeg; ob < oend; ob += 4) {
        // phase A: product images for up to 4 offsets
        #pragma unroll
        for (int b = 0; b < 4; ++b) {
            int o = ob + b;
            if (o >= oend) break;
            u32 oy = (u32)o / 15u; u32 ox = (u32)o - oy*15u;
            float4 sv = sP[(a0r + (int)oy)*SPS + (a0c + (int)ox)];
            h[b][a0r*HS + a0c] = b0.x*sv.x + b0.y*sv.y + b0.z*sv.z;
            if (has1) {
                float4 sw = sP[(a1r + (int)oy)*SPS + (a1c + (int)ox)];
                h[b][a1r*HS + a1c] = b1.x*sw.x + b1.y*sw.y + b1.z*sw.z;
            }
        }
        __syncthreads();
        // phase B: vertical 5-sums, float4 (320 tasks over 256 threads)
        {
            const float* hb = h[pb_b] + pb_r*HS + pb_cg*4;
            float4 acc = *(const float4*)hb;
            #pragma unroll
            for (int p = 1; p < PS_; ++p) {
                float4 v = *(const float4*)(hb + p*HS);
                acc.x += v.x; acc.y += v.y; acc.z += v.z; acc.w += v.w;
            }
            *(float4*)(cs[pb_b] + pb_r*CSS + pb_cg*4) = acc;
            if (tid < 64) {
                const float* hb2 = h[pb2_b] + pb2_r*HS + pb2_cg*4;
                float4 a2 = *(const float4*)hb2;
                #pragma unroll
                for (int p = 1; p < PS_; ++p) {
                    float4 v = *(const float4*)(hb2 + p*HS);
                    a2.x += v.x; a2.y += v.y; a2.z += v.z; a2.w += v.w;
                }
                *(float4*)(cs[pb2_b] + pb2_r*CSS + pb2_cg*4) = a2;
            }
        }
        __syncthreads();
        // phase C: horizontal 5-sum + distance + key insert
        #pragma unroll
        for (int b = 0; b < 4; ++b) {
            int o = ob + b;
            if (o >= oend) break;
            u32 oy = (u32)o / 15u; u32 ox = (u32)o - oy*15u;
            const float* cr = cs[b] + ty*CSS + tx;
            float V = cr[0] + cr[1] + cr[2] + cr[3] + cr[4];
            float d = fmaxf(Sbase + sS[(ty + (int)oy)*SSS + (tx + (int)ox)] - 2.f*V, 0.f);
            u32 key = (__float_as_uint(d) & 0xFFFFFF00u) | (u32)o;
            if (key < kb[K_-1]) {
                kb[K_-1] = key;
                #pragma unroll
                for (int k = K_-1; k > 0; --k) {
                    if (kb[k] < kb[k-1]) { u32 tk = kb[k]; kb[k] = kb[k-1]; kb[k-1] = tk; }
                }
            }
        }
    }

    int px = ((t*H_ + i0 + ty)*W_ + j0 + tx);
    uint4* pk = pkey + ((size_t)q*NPIX + px)*4;
    pk[0] = make_uint4(kb[0],  kb[1],  kb[2],  kb[3]);
    pk[1] = make_uint4(kb[4],  kb[5],  kb[6],  kb[7]);
    pk[2] = make_uint4(kb[8],  kb[9],  kb[10], kb[11]);
    pk[3] = make_uint4(kb[12], kb[13], 0xFFFFFFFFu, 0xFFFFFFFFu);
}

// ---------------- Kernel 6: merge quarters + softmax ----------------
__global__ __launch_bounds__(256) void merge_kernel(const uint4* __restrict__ pkey,
                                                    const float* __restrict__ sigma,
                                                    float* __restrict__ wts,
                                                    uint4* __restrict__ idxpack) {
    int px = blockIdx.x*256 + threadIdx.x;

    u32 kb[K_];
    {
        const uint4* pk = pkey + (size_t)px*4;
        uint4 v0=pk[0], v1=pk[1], v2=pk[2], v3=pk[3];
        kb[0]=v0.x; kb[1]=v0.y; kb[2]=v0.z; kb[3]=v0.w;
        kb[4]=v1.x; kb[5]=v1.y; kb[6]=v1.z; kb[7]=v1.w;
        kb[8]=v2.x; kb[9]=v2.y; kb[10]=v2.z; kb[11]=v2.w;
        kb[12]=v3.x; kb[13]=v3.y;
    }
    for (int qq = 1; qq < NQ; ++qq) {
        const uint4* pk = pkey + ((size_t)qq*NPIX + px)*4;
        uint4 v0=pk[0], v1=pk[1], v2=pk[2], v3=pk[3];
        u32 cand[K_] = {v0.x,v0.y,v0.z,v0.w, v1.x,v1.y,v1.z,v1.w,
                        v2.x,v2.y,v2.z,v2.w, v3.x,v3.y};
        #pragma unroll
        for (int k = 0; k < K_; ++k) {
            u32 c = cand[k];
            if (c >= kb[K_-1]) break;      // candidates sorted ascending
            kb[K_-1] = c;
            #pragma unroll
            for (int j = K_-1; j > 0; --j) {
                if (kb[j] < kb[j-1]) { u32 tk = kb[j]; kb[j] = kb[j-1]; kb[j-1] = tk; }
            }
        }
    }

    float sig = sigma[0] * (1.0f/255.0f) * 2.0f;
    float denom = 2.0f * (float)(C_*PS_*PS_) * (sig*sig) + 1e-8f;
    float d0 = __uint_as_float(kb[0] & 0xFFFFFF00u);
    float w[K_]; float sum = 0.f;
    #pragma unroll
    for (int k = 0; k < K_; ++k) {
        float d = __uint_as_float(kb[k] & 0xFFFFFF00u);
        w[k] = expf(-(d - d0) / denom); sum += w[k];
    }
    float inv = 1.0f / sum;

    float4* wv = (float4*)(wts + (size_t)px*16);
    wv[0] = make_float4(w[0]*inv,  w[1]*inv,  w[2]*inv,  w[3]*inv);
    wv[1] = make_float4(w[4]*inv,  w[5]*inv,  w[6]*inv,  w[7]*inv);
    wv[2] = make_float4(w[8]*inv,  w[9]*inv,  w[10]*inv, w[11]*inv);
    wv[3] = make_float4(w[12]*inv, w[13]*inv, 0.f, 0.f);
    uint4 iv;
    iv.x = (kb[0]&255u)  | ((kb[1]&255u)<<8)  | ((kb[2]&255u)<<16)  | ((kb[3]&255u)<<24);
    iv.y = (kb[4]&255u)  | ((kb[5]&255u)<<8)  | ((kb[6]&255u)<<16)  | ((kb[7]&255u)<<24);
    iv.z = (kb[8]&255u)  | ((kb[9]&255u)<<8)  | ((kb[10]&255u)<<16) | ((kb[11]&255u)<<24);
    iv.w = (kb[12]&255u) | ((kb[13]&255u)<<8);
    idxpack[px] = iv;
}

// ---------------- Kernel 7: gather-aggregate, LDS-staged, 4 threads/pixel ----------------
// output padded coord y = i + PW_; contributing queries qi = y - a, a in [0,5)
__global__ __launch_bounds__(256) void agg_kernel(const float4* __restrict__ P4,
                                                  const float* __restrict__ wts,
                                                  const uint4* __restrict__ idxpack,
                                                  const float* __restrict__ means,
                                                  float* __restrict__ out) {
    __shared__ float4 sPg[APR*APS];
    __shared__ float  sWt[AWR*AWR*AWS];
    __shared__ uint4  sIx[AWR*AWR];

    const int tid = threadIdx.x;
    const int part = tid & 3;
    const int lp = tid >> 2;                  // 0..63 local pixel
    const int tx = lp & 7, ty = lp >> 3;
    const int i0 = blockIdx.y * AT, j0 = blockIdx.x * AT;
    const int t = blockIdx.z;
    const float4* Pt = P4 + (size_t)t*(HP_*HP_);

    for (int e = tid; e < APR*APR; e += 256) {
        int r = e / APR, c = e % APR;
        sPg[r*APS + c] = Pt[(i0 + 2 + r)*HP_ + (j0 + 2 + c)];
    }
    // staged query window: qi = i0 - 2 + r  (covers i + PW_ - a for a in [0,5))
    for (int e = tid; e < AWR*AWR; e += 256) {
        int r = e / AWR, c = e % AWR;
        int qi = i0 - 2 + r, qj = j0 - 2 + c;
        if (qi >= 0 && qi < H_ && qj >= 0 && qj < W_) {
            size_t qq = ((size_t)t*H_ + qi)*W_ + qj;
            const float4* wsrc = (const float4*)&wts[qq*16];
            float4* dst = (float4*)&sWt[e*AWS];
            dst[0] = wsrc[0]; dst[1] = wsrc[1]; dst[2] = wsrc[2]; dst[3] = wsrc[3];
            sIx[e] = idxpack[qq];
        }
    }
    __syncthreads();

    const int i = i0 + ty, j = j0 + tx;
    float s0 = 0.f, s1 = 0.f, s2 = 0.f, cnt = 0.f;
    for (int ab = part; ab < 25; ab += 4) {
        int a = ab / 5, b = ab % 5;
        int qi = i + PW_ - a, qj = j + PW_ - b;
        if (qi < 0 || qi >= H_ || qj < 0 || qj >= W_) continue;
        cnt += 1.f;
        int le = (ty + 4 - a)*AWR + (tx + 4 - b);   // (qi - (i0-2)) = ty + 4 - a
        const float4* wv = (const float4*)&sWt[le*AWS];
        float4 wa = wv[0], wb = wv[1], wc = wv[2], wd = wv[3];
        uint4 ip = sIx[le];
        #define ACC(wval, obits) { \
            u32 o_ = (obits); \
            u32 oy_ = o_ / 15u; u32 ox_ = o_ - oy_*15u; \
            float4 v_ = sPg[(ty + (int)oy_)*APS + tx + (int)ox_]; \
            float w_ = (wval); \
            s0 += w_ * v_.x; s1 += w_ * v_.y; s2 += w_ * v_.z; }
        ACC(wa.x, ip.x & 255u);       ACC(wa.y, (ip.x>>8) & 255u);
        ACC(wa.z, (ip.x>>16) & 255u); ACC(wa.w, ip.x>>24);
        ACC(wb.x, ip.y & 255u);       ACC(wb.y, (ip.y>>8) & 255u);
        ACC(wb.z, (ip.y>>16) & 255u); ACC(wb.w, ip.y>>24);
        ACC(wc.x, ip.z & 255u);       ACC(wc.y, (ip.z>>8) & 255u);
        ACC(wc.z, (ip.z>>16) & 255u); ACC(wc.w, ip.z>>24);
        ACC(wd.x, ip.w & 255u);       ACC(wd.y, (ip.w>>8) & 255u);
        #undef ACC
    }

    s0 += __shfl_xor(s0, 1, 64); s0 += __shfl_xor(s0, 2, 64);
    s1 += __shfl_xor(s1, 1, 64); s1 += __shfl_xor(s1, 2, 64);
    s2 += __shfl_xor(s2, 1, 64); s2 += __shfl_xor(s2, 2, 64);
    cnt += __shfl_xor(cnt, 1, 64); cnt += __shfl_xor(cnt, 2, 64);

    if (part == 0) {
        float invc = 1.0f / (cnt + 1e-10f);
        float m0 = means[t*3+0], m1 = means[t*3+1], m2 = means[t*3+2];
        size_t obase = (size_t)t*(C_*H_*W_) + (size_t)i*W_ + j;
        out[obase]             = 127.5f * (s0*invc + m0 + 1.0f);
        out[obase +   H_*W_]   = 127.5f * (s1*invc + m1 + 1.0f);
        out[obase + 2*(H_*W_)] = 127.5f * (s2*invc + m2 + 1.0f);
    }
}

extern "C" void kernel_launch(void* const* d_in, const int* in_sizes, int n_in,
                              void* d_out, int out_size, void* d_ws, size_t ws_size,
                              hipStream_t stream) {
    const float* noisy = (const float*)d_in[0];
    const float* sigma = (const float*)d_in[1];
    float* out = (float*)d_out;
    float* ws  = (float*)d_ws;

    // ws layout (float offsets, all 16B aligned):
    float*  means   = ws;                               // 16
    float4* P4      = (float4*)(ws + 16);               // 341056 floats
    float*  colq    = ws + 16 + 341056;                 // 82928 -> pad 82944
    float*  S       = ws + 16 + 341056 + 82944;         // 80656
    float*  wts     = ws + 16 + 341056 + 82944 + 80656; // 1048576
    uint4*  idxpack = (uint4*)(wts + 1048576);          // 262144 floats
    uint4*  pkey    = (uint4*)((float*)idxpack + 262144); // 4*NPIX*16 u32 = 4194304
    // total ~6.01M floats ~ 24.0 MB

    hipLaunchKernelGGL(means_kernel, dim3(T_*C_), dim3(256), 0, stream, noisy, means);

    int padN = T_*HP_*HP_;
    hipLaunchKernelGGL(pad4_kernel, dim3((padN + 255)/256), dim3(256), 0, stream,
                       noisy, means, P4);

    int cqN = T_*SD_*HP_;
    hipLaunchKernelGGL(colq_kernel, dim3((cqN + 255)/256), dim3(256), 0, stream, P4, colq);

    int sN = T_*SD_*SD_;
    hipLaunchKernelGGL(s_kernel, dim3((sN + 255)/256), dim3(256), 0, stream, colq, S);

    hipLaunchKernelGGL(fused_topk, dim3(W_/TILE, H_/TILE, T_*NQ), dim3(256), 0, stream,
                       P4, S, pkey);

    hipLaunchKernelGGL(merge_kernel, dim3(NPIX/256), dim3(256), 0, stream,
                       pkey, sigma, wts, idxpack);

    hipLaunchKernelGGL(agg_kernel, dim3(W_/AT, H_/AT, T_), dim3(256), 0, stream,
                       P4, wts, idxpack, means, out);
}

// Round 6
// 103.724 us; speedup vs baseline: 2.8067x; 1.0220x over previous
//
#include <hip/hip_runtime.h>

#define T_ 4
#define C_ 3
#define H_ 128
#define W_ 128
#define PS_ 5
#define K_ 14
#define WS_ 15
#define SW_ 7
#define PW_ 2
#define RAD_ 9
#define HP_ 146          // H_ + 2*RAD_
#define NOFF 225
#define NPIX (T_*H_*W_)  // 65536
#define NQ 4

#define TILE 16
#define SPR 34           // sP rows/cols (pixels)
#define SPS 37           // sP row stride (float4s) - rotates banks
#define SSR 30           // sS rows/cols
#define SSS 33           // sS row stride
#define OB 8             // offsets per batch
#define CSS 21           // cs col stride (floats)
#define CSOG (16*CSS)    // cs per-offset size = 336

#define AT 8             // agg tile
#define APR 22           // staged P4 rows (AT + 14)
#define APS 23           // staged P4 stride (float4s)
#define AWR 12           // staged wts rows (AT + 4)
#define AWS 20           // staged wts stride per pixel (floats)

typedef unsigned int u32;

// ---------------- Kernel 1: per-(t,c) means ----------------
__global__ __launch_bounds__(256) void means_kernel(const float* __restrict__ noisy,
                                                    float* __restrict__ means) {
    int tc = blockIdx.x;
    const float* img = noisy + (size_t)tc * (H_*W_);
    float s = 0.f;
    for (int e = threadIdx.x; e < H_*W_; e += 256) s += img[e];
    #pragma unroll
    for (int off = 32; off; off >>= 1) s += __shfl_down(s, off, 64);
    __shared__ float red[4];
    int lane = threadIdx.x & 63, wv = threadIdx.x >> 6;
    if (lane == 0) red[wv] = s;
    __syncthreads();
    if (threadIdx.x == 0) {
        float tot = red[0] + red[1] + red[2] + red[3];
        means[tc] = tot / (float)(H_*W_) * (1.0f/127.5f) - 1.0f;
    }
}

// ---------------- Kernel 2: normalize + mean-subtract + reflect pad, interleaved float4 ----------------
__global__ __launch_bounds__(256) void pad4_kernel(const float* __restrict__ noisy,
                                                   const float* __restrict__ means,
                                                   float4* __restrict__ P4) {
    int e = blockIdx.x * 256 + threadIdx.x;
    if (e >= T_*HP_*HP_) return;
    int x = e % HP_;
    int y = (e / HP_) % HP_;
    int t = e / (HP_*HP_);
    int ry = y - RAD_; if (ry < 0) ry = -ry; else if (ry > H_-1) ry = 2*(H_-1) - ry;
    int rx = x - RAD_; if (rx < 0) rx = -rx; else if (rx > W_-1) rx = 2*(W_-1) - rx;
    const float* nt = noisy + (size_t)t*(C_*H_*W_) + ry*W_ + rx;
    float4 v;
    v.x = nt[0]         * (1.0f/127.5f) - 1.0f - means[t*3+0];
    v.y = nt[H_*W_]     * (1.0f/127.5f) - 1.0f - means[t*3+1];
    v.z = nt[2*(H_*W_)] * (1.0f/127.5f) - 1.0f - means[t*3+2];
    v.w = 0.f;
    P4[e] = v;
}

// ---------------- Kernel 3: fused S + distance + top-K over an offset quarter ----------------
// d_true(pixel, o) = S_base + S_shift(o) - 2*box5(h_o)   (clamped >= 0)
// key = (bits(d) & 0xFFFFFF00) | o  -> uint order == (d, o) lexicographic
__global__ __launch_bounds__(256) void fused_topk(const float4* __restrict__ P4,
                                                  uint4* __restrict__ pkey) {
    __shared__ float4 sP[SPR*SPS];     // 20128 B
    __shared__ float  sS[SSR*SSS];     //  3960 B
    __shared__ float  cs[OB*CSOG];     // 10752 B (also init scratch: q, colq)

    const int tid = threadIdx.x;
    const int tx = tid & 15, ty = tid >> 4;
    const int z = blockIdx.z;                 // 0..15
    const int t = z >> 2, q = z & 3;
    const int i0 = blockIdx.y * TILE, j0 = blockIdx.x * TILE;
    const float4* Pt = P4 + (size_t)t * (HP_*HP_);

    // stage P tile
    for (int e = tid; e < SPR*SPR; e += 256) {
        int r = e / SPR, c = e % SPR;
        sP[r*SPS + c] = Pt[(i0 + r)*HP_ + (j0 + c)];
    }
    __syncthreads();

    // in-block S: qsq (34x34, stride 35) -> colq (30x34, stride 35) -> sS (30x30)
    {
        float* qsq = cs;               // [0, 1190)
        float* cq  = cs + 1200;        // [1200, 2250)
        for (int e = tid; e < 34*34; e += 256) {
            int r = e / 34, c = e - r*34;
            float4 v = sP[r*SPS + c];
            qsq[r*35 + c] = v.x*v.x + v.y*v.y + v.z*v.z;
        }
        __syncthreads();
        for (int e = tid; e < 30*34; e += 256) {
            int r = e / 34, c = e - r*34;
            const float* qp = &qsq[r*35 + c];
            cq[r*35 + c] = qp[0] + qp[35] + qp[70] + qp[105] + qp[140];
        }
        __syncthreads();
        for (int e = tid; e < 30*30; e += 256) {
            int r = e / 30, c = e - r*30;
            const float* cp = &cq[r*35 + c];
            sS[r*SSS + c] = cp[0] + cp[1] + cp[2] + cp[3] + cp[4];
        }
        __syncthreads();
    }

    const float Sbase = sS[(ty + SW_)*SSS + (tx + SW_)];

    const int og = tid / 20;
    const int cc = tid - og*20;
    const bool p1act = (tid < OB*20);

    u32 kb[K_];
    #pragma unroll
    for (int k = 0; k < K_; ++k) kb[k] = 0xFFFFFFFFu;

    const int obeg = (q == 0) ? 0 : 57 + (q-1)*56;
    const int oend = obeg + ((q == 0) ? 57 : 56);

    for (int ob = obeg; ob < oend; ob += OB) {
        // pass 1: per-(offset,column) vertical box sums, register sliding window
        int o = ob + og;
        if (p1act && o < oend) {
            u32 oy = (u32)o / 15u, ox = (u32)o - oy*15u;
            const float4* bp = &sP[SW_*SPS + (cc + SW_)];
            const float4* sp = &sP[(int)oy*SPS + (cc + (int)ox)];
            float h[20];
            #pragma unroll
            for (int r = 0; r < 20; ++r) {
                float4 bv = bp[r*SPS];
                float4 sv = sp[r*SPS];
                h[r] = bv.x*sv.x + bv.y*sv.y + bv.z*sv.z;
            }
            float run = h[0] + h[1] + h[2] + h[3] + h[4];
            float* crow = &cs[og*CSOG + cc];
            crow[0] = run;
            #pragma unroll
            for (int i = 1; i < 16; ++i) {
                run += h[i+4] - h[i-1];
                crow[i*CSS] = run;
            }
        }
        __syncthreads();
        // pass 2: per-pixel horizontal 5-sum + distance + key insert
        for (int g = 0; g < OB; ++g) {
            int o2 = ob + g;
            if (o2 >= oend) break;
            u32 oy2 = (u32)o2 / 15u, ox2 = (u32)o2 - oy2*15u;
            const float* cr = &cs[g*CSOG + ty*CSS + tx];
            float V = cr[0] + cr[1] + cr[2] + cr[3] + cr[4];
            float d = fmaxf(Sbase + sS[(ty + (int)oy2)*SSS + (tx + (int)ox2)] - 2.f*V, 0.f);
            u32 key = (__float_as_uint(d) & 0xFFFFFF00u) | (u32)o2;
            if (key < kb[K_-1]) {
                kb[K_-1] = key;
                #pragma unroll
                for (int k = K_-1; k > 0; --k) {
                    if (kb[k] < kb[k-1]) { u32 tk = kb[k]; kb[k] = kb[k-1]; kb[k-1] = tk; }
                }
            }
        }
        __syncthreads();
    }

    int px = ((t*H_ + i0 + ty)*W_ + j0 + tx);
    uint4* pk = pkey + ((size_t)q*NPIX + px)*4;
    pk[0] = make_uint4(kb[0],  kb[1],  kb[2],  kb[3]);
    pk[1] = make_uint4(kb[4],  kb[5],  kb[6],  kb[7]);
    pk[2] = make_uint4(kb[8],  kb[9],  kb[10], kb[11]);
    pk[3] = make_uint4(kb[12], kb[13], 0xFFFFFFFFu, 0xFFFFFFFFu);
}

// ---------------- Kernel 4: merge quarters + softmax ----------------
__global__ __launch_bounds__(256) void merge_kernel(const uint4* __restrict__ pkey,
                                                    const float* __restrict__ sigma,
                                                    float* __restrict__ wts,
                                                    uint4* __restrict__ idxpack) {
    int px = blockIdx.x*256 + threadIdx.x;

    u32 kb[K_];
    {
        const uint4* pk = pkey + (size_t)px*4;
        uint4 v0=pk[0], v1=pk[1], v2=pk[2], v3=pk[3];
        kb[0]=v0.x; kb[1]=v0.y; kb[2]=v0.z; kb[3]=v0.w;
        kb[4]=v1.x; kb[5]=v1.y; kb[6]=v1.z; kb[7]=v1.w;
        kb[8]=v2.x; kb[9]=v2.y; kb[10]=v2.z; kb[11]=v2.w;
        kb[12]=v3.x; kb[13]=v3.y;
    }
    for (int qq = 1; qq < NQ; ++qq) {
        const uint4* pk = pkey + ((size_t)qq*NPIX + px)*4;
        uint4 v0=pk[0], v1=pk[1], v2=pk[2], v3=pk[3];
        u32 cand[K_] = {v0.x,v0.y,v0.z,v0.w, v1.x,v1.y,v1.z,v1.w,
                        v2.x,v2.y,v2.z,v2.w, v3.x,v3.y};
        #pragma unroll
        for (int k = 0; k < K_; ++k) {
            u32 c = cand[k];
            if (c >= kb[K_-1]) break;      // candidates sorted ascending
            kb[K_-1] = c;
            #pragma unroll
            for (int j = K_-1; j > 0; --j) {
                if (kb[j] < kb[j-1]) { u32 tk = kb[j]; kb[j] = kb[j-1]; kb[j-1] = tk; }
            }
        }
    }

    float sig = sigma[0] * (1.0f/255.0f) * 2.0f;
    float denom = 2.0f * (float)(C_*PS_*PS_) * (sig*sig) + 1e-8f;
    float d0 = __uint_as_float(kb[0] & 0xFFFFFF00u);
    float w[K_]; float sum = 0.f;
    #pragma unroll
    for (int k = 0; k < K_; ++k) {
        float d = __uint_as_float(kb[k] & 0xFFFFFF00u);
        w[k] = expf(-(d - d0) / denom); sum += w[k];
    }
    float inv = 1.0f / sum;

    float4* wv = (float4*)(wts + (size_t)px*16);
    wv[0] = make_float4(w[0]*inv,  w[1]*inv,  w[2]*inv,  w[3]*inv);
    wv[1] = make_float4(w[4]*inv,  w[5]*inv,  w[6]*inv,  w[7]*inv);
    wv[2] = make_float4(w[8]*inv,  w[9]*inv,  w[10]*inv, w[11]*inv);
    wv[3] = make_float4(w[12]*inv, w[13]*inv, 0.f, 0.f);
    uint4 iv;
    iv.x = (kb[0]&255u)  | ((kb[1]&255u)<<8)  | ((kb[2]&255u)<<16)  | ((kb[3]&255u)<<24);
    iv.y = (kb[4]&255u)  | ((kb[5]&255u)<<8)  | ((kb[6]&255u)<<16)  | ((kb[7]&255u)<<24);
    iv.z = (kb[8]&255u)  | ((kb[9]&255u)<<8)  | ((kb[10]&255u)<<16) | ((kb[11]&255u)<<24);
    iv.w = (kb[12]&255u) | ((kb[13]&255u)<<8);
    idxpack[px] = iv;
}

// ---------------- Kernel 5: gather-aggregate, LDS-staged, 4 threads/pixel ----------------
// output padded coord y = i + PW_; contributing queries qi = y - a, a in [0,5)
__global__ __launch_bounds__(256) void agg_kernel(const float4* __restrict__ P4,
                                                  const float* __restrict__ wts,
                                                  const uint4* __restrict__ idxpack,
                                                  const float* __restrict__ means,
                                                  float* __restrict__ out) {
    __shared__ float4 sPg[APR*APS];
    __shared__ float  sWt[AWR*AWR*AWS];
    __shared__ uint4  sIx[AWR*AWR];

    const int tid = threadIdx.x;
    const int part = tid & 3;
    const int lp = tid >> 2;                  // 0..63 local pixel
    const int tx = lp & 7, ty = lp >> 3;
    const int i0 = blockIdx.y * AT, j0 = blockIdx.x * AT;
    const int t = blockIdx.z;
    const float4* Pt = P4 + (size_t)t*(HP_*HP_);

    for (int e = tid; e < APR*APR; e += 256) {
        int r = e / APR, c = e % APR;
        sPg[r*APS + c] = Pt[(i0 + 2 + r)*HP_ + (j0 + 2 + c)];
    }
    // staged query window: qi = i0 - 2 + r  (covers i + PW_ - a for a in [0,5))
    for (int e = tid; e < AWR*AWR; e += 256) {
        int r = e / AWR, c = e % AWR;
        int qi = i0 - 2 + r, qj = j0 - 2 + c;
        if (qi >= 0 && qi < H_ && qj >= 0 && qj < W_) {
            size_t qq = ((size_t)t*H_ + qi)*W_ + qj;
            const float4* wsrc = (const float4*)&wts[qq*16];
            float4* dst = (float4*)&sWt[e*AWS];
            dst[0] = wsrc[0]; dst[1] = wsrc[1]; dst[2] = wsrc[2]; dst[3] = wsrc[3];
            sIx[e] = idxpack[qq];
        }
    }
    __syncthreads();

    const int i = i0 + ty, j = j0 + tx;
    float s0 = 0.f, s1 = 0.f, s2 = 0.f, cnt = 0.f;
    for (int ab = part; ab < 25; ab += 4) {
        int a = ab / 5, b = ab % 5;
        int qi = i + PW_ - a, qj = j + PW_ - b;
        if (qi < 0 || qi >= H_ || qj < 0 || qj >= W_) continue;
        cnt += 1.f;
        int le = (ty + 4 - a)*AWR + (tx + 4 - b);   // (qi - (i0-2)) = ty + 4 - a
        const float4* wv = (const float4*)&sWt[le*AWS];
        float4 wa = wv[0], wb = wv[1], wc = wv[2], wd = wv[3];
        uint4 ip = sIx[le];
        #define ACC(wval, obits) { \
            u32 o_ = (obits); \
            u32 oy_ = o_ / 15u; u32 ox_ = o_ - oy_*15u; \
            float4 v_ = sPg[(ty + (int)oy_)*APS + tx + (int)ox_]; \
            float w_ = (wval); \
            s0 += w_ * v_.x; s1 += w_ * v_.y; s2 += w_ * v_.z; }
        ACC(wa.x, ip.x & 255u);       ACC(wa.y, (ip.x>>8) & 255u);
        ACC(wa.z, (ip.x>>16) & 255u); ACC(wa.w, ip.x>>24);
        ACC(wb.x, ip.y & 255u);       ACC(wb.y, (ip.y>>8) & 255u);
        ACC(wb.z, (ip.y>>16) & 255u); ACC(wb.w, ip.y>>24);
        ACC(wc.x, ip.z & 255u);       ACC(wc.y, (ip.z>>8) & 255u);
        ACC(wc.z, (ip.z>>16) & 255u); ACC(wc.w, ip.z>>24);
        ACC(wd.x, ip.w & 255u);       ACC(wd.y, (ip.w>>8) & 255u);
        #undef ACC
    }

    s0 += __shfl_xor(s0, 1, 64); s0 += __shfl_xor(s0, 2, 64);
    s1 += __shfl_xor(s1, 1, 64); s1 += __shfl_xor(s1, 2, 64);
    s2 += __shfl_xor(s2, 1, 64); s2 += __shfl_xor(s2, 2, 64);
    cnt += __shfl_xor(cnt, 1, 64); cnt += __shfl_xor(cnt, 2, 64);

    if (part == 0) {
        float invc = 1.0f / (cnt + 1e-10f);
        float m0 = means[t*3+0], m1 = means[t*3+1], m2 = means[t*3+2];
        size_t obase = (size_t)t*(C_*H_*W_) + (size_t)i*W_ + j;
        out[obase]             = 127.5f * (s0*invc + m0 + 1.0f);
        out[obase +   H_*W_]   = 127.5f * (s1*invc + m1 + 1.0f);
        out[obase + 2*(H_*W_)] = 127.5f * (s2*invc + m2 + 1.0f);
    }
}

extern "C" void kernel_launch(void* const* d_in, const int* in_sizes, int n_in,
                              void* d_out, int out_size, void* d_ws, size_t ws_size,
                              hipStream_t stream) {
    const float* noisy = (const float*)d_in[0];
    const float* sigma = (const float*)d_in[1];
    float* out = (float*)d_out;
    float* ws  = (float*)d_ws;

    // ws layout (float offsets, all 16B aligned):
    float*  means   = ws;                               // 16
    float4* P4      = (float4*)(ws + 16);               // 341056 floats
    float*  wts     = ws + 16 + 341056;                 // 1048576
    uint4*  idxpack = (uint4*)(wts + 1048576);          // 262144 floats
    uint4*  pkey    = (uint4*)((float*)idxpack + 262144); // 4*NPIX*16 u32 = 4194304 floats
    // total ~5.85M floats ~ 23.4 MB

    hipLaunchKernelGGL(means_kernel, dim3(T_*C_), dim3(256), 0, stream, noisy, means);

    int padN = T_*HP_*HP_;
    hipLaunchKernelGGL(pad4_kernel, dim3((padN + 255)/256), dim3(256), 0, stream,
                       noisy, means, P4);

    hipLaunchKernelGGL(fused_topk, dim3(W_/TILE, H_/TILE, T_*NQ), dim3(256), 0, stream,
                       P4, pkey);

    hipLaunchKernelGGL(merge_kernel, dim3(NPIX/256), dim3(256), 0, stream,
                       pkey, sigma, wts, idxpack);

    hipLaunchKernelGGL(agg_kernel, dim3(W_/AT, H_/AT, T_), dim3(256), 0, stream,
                       P4, wts, idxpack, means, out);
}

// Round 7
// 90.240 us; speedup vs baseline: 3.2260x; 1.1494x over previous
//
#include <hip/hip_runtime.h>

#define T_ 4
#define C_ 3
#define H_ 128
#define W_ 128
#define PS_ 5
#define K_ 14
#define WS_ 15
#define SW_ 7
#define PW_ 2
#define RAD_ 9
#define HP_ 146          // H_ + 2*RAD_
#define NOFF 225
#define NPIX (T_*H_*W_)  // 65536
#define NQ 2

#define TILE 16
#define SPR 34           // sP rows/cols (pixels)
#define SPS 37           // sP row stride (float4s) - rotates banks
#define SSR 30           // sS rows/cols
#define SSS 33           // sS row stride
#define OB 12            // offsets per batch (OB*20 = 240 <= 256)
#define CSOG 324         // cs per-offset stride (16 rows * 20 + 4 pad; %32==4 for bank stagger)

#define AT 8             // agg tile
#define APR 22           // staged P4 rows (AT + 14)
#define APS 23           // staged P4 stride (float4s)
#define AWR 12           // staged wts rows (AT + 4)
#define AWS 20           // staged wts stride per pixel (floats)

typedef unsigned int u32;

// ---------------- Kernel 1: per-(t,c) means ----------------
__global__ __launch_bounds__(256) void means_kernel(const float* __restrict__ noisy,
                                                    float* __restrict__ means) {
    int tc = blockIdx.x;
    const float* img = noisy + (size_t)tc * (H_*W_);
    float s = 0.f;
    for (int e = threadIdx.x; e < H_*W_; e += 256) s += img[e];
    #pragma unroll
    for (int off = 32; off; off >>= 1) s += __shfl_down(s, off, 64);
    __shared__ float red[4];
    int lane = threadIdx.x & 63, wv = threadIdx.x >> 6;
    if (lane == 0) red[wv] = s;
    __syncthreads();
    if (threadIdx.x == 0) {
        float tot = red[0] + red[1] + red[2] + red[3];
        means[tc] = tot / (float)(H_*W_) * (1.0f/127.5f) - 1.0f;
    }
}

// ---------------- Kernel 2: normalize + mean-subtract + reflect pad, interleaved float4 ----------------
__global__ __launch_bounds__(256) void pad4_kernel(const float* __restrict__ noisy,
                                                   const float* __restrict__ means,
                                                   float4* __restrict__ P4) {
    int e = blockIdx.x * 256 + threadIdx.x;
    if (e >= T_*HP_*HP_) return;
    int x = e % HP_;
    int y = (e / HP_) % HP_;
    int t = e / (HP_*HP_);
    int ry = y - RAD_; if (ry < 0) ry = -ry; else if (ry > H_-1) ry = 2*(H_-1) - ry;
    int rx = x - RAD_; if (rx < 0) rx = -rx; else if (rx > W_-1) rx = 2*(W_-1) - rx;
    const float* nt = noisy + (size_t)t*(C_*H_*W_) + ry*W_ + rx;
    float4 v;
    v.x = nt[0]         * (1.0f/127.5f) - 1.0f - means[t*3+0];
    v.y = nt[H_*W_]     * (1.0f/127.5f) - 1.0f - means[t*3+1];
    v.z = nt[2*(H_*W_)] * (1.0f/127.5f) - 1.0f - means[t*3+2];
    v.w = 0.f;
    P4[e] = v;
}

// ---------------- Kernel 3: fused S + distance + top-K over an offset half ----------------
// d_true(pixel, o) = S_base + S_shift(o) - 2*box5(h_o)   (clamped >= 0)
// key = (bits(d) & 0xFFFFFF00) | o  -> uint order == (d, o) lexicographic
__global__ __launch_bounds__(256, 4) void fused_topk(const float4* __restrict__ P4,
                                                     uint4* __restrict__ pkey) {
    __shared__ float4 sP[SPR*SPS];     // 20128 B
    __shared__ float  sS[SSR*SSS];     //  3960 B
    __shared__ float  cs[OB*CSOG];     // 15552 B (also init scratch: qsq, colq)

    const int tid = threadIdx.x;
    const int tx = tid & 15, ty = tid >> 4;
    const int z = blockIdx.z;                 // 0..7
    const int t = z >> 1, q = z & 1;
    const int i0 = blockIdx.y * TILE, j0 = blockIdx.x * TILE;
    const float4* Pt = P4 + (size_t)t * (HP_*HP_);

    // stage P tile
    for (int e = tid; e < SPR*SPR; e += 256) {
        int r = e / SPR, c = e % SPR;
        sP[r*SPS + c] = Pt[(i0 + r)*HP_ + (j0 + c)];
    }
    __syncthreads();

    // in-block S: qsq (34x34, stride 35) -> colq (30x34, stride 35) -> sS (30x30)
    {
        float* qsq = cs;               // [0, 1190)
        float* cq  = cs + 1200;        // [1200, 2250)
        for (int e = tid; e < 34*34; e += 256) {
            int r = e / 34, c = e - r*34;
            float4 v = sP[r*SPS + c];
            qsq[r*35 + c] = v.x*v.x + v.y*v.y + v.z*v.z;
        }
        __syncthreads();
        for (int e = tid; e < 30*34; e += 256) {
            int r = e / 34, c = e - r*34;
            const float* qp = &qsq[r*35 + c];
            cq[r*35 + c] = qp[0] + qp[35] + qp[70] + qp[105] + qp[140];
        }
        __syncthreads();
        for (int e = tid; e < 30*30; e += 256) {
            int r = e / 30, c = e - r*30;
            const float* cp = &cq[r*35 + c];
            sS[r*SSS + c] = cp[0] + cp[1] + cp[2] + cp[3] + cp[4];
        }
        __syncthreads();
    }

    const float Sbase = sS[(ty + SW_)*SSS + (tx + SW_)];

    // pass-1 role: thread = (offset og, column cc); base column cached in registers
    const int og = tid / 20;
    const int cc = tid - og*20;
    const bool p1act = (tid < OB*20);
    float bx[20], by[20], bz[20];
    if (p1act) {
        #pragma unroll
        for (int r = 0; r < 20; ++r) {
            float4 v = sP[(SW_ + r)*SPS + (cc + SW_)];
            bx[r] = v.x; by[r] = v.y; bz[r] = v.z;
        }
    }
    float* myv = &cs[og*CSOG + cc];

    // pass-2 role: thread = (offset p2o, row p2i)
    const int p2o = tid >> 4;          // 0..15 (valid < OB)
    const int p2i = tid & 15;
    const bool p2act = (p2o < OB);
    float* p2row = &cs[p2o*CSOG + p2i*20];

    // pass-3 base pointer
    const float* vb = &cs[ty*20 + tx];

    u32 kb[K_];
    #pragma unroll
    for (int k = 0; k < K_; ++k) kb[k] = 0xFFFFFFFFu;

    const int obeg = q ? 113 : 0;
    const int oend = q ? 225 : 113;

    for (int ob = obeg; ob < oend; ob += OB) {
        // pass 1: vertical box sums (register sliding window), shift-only LDS reads
        int o = ob + og;
        if (p1act && o < oend) {
            u32 oyu = (u32)o / 15u, oxu = (u32)o - oyu*15u;
            const float4* sp = &sP[(int)oyu*SPS + cc + (int)oxu];
            float ring[5]; float run = 0.f;
            #pragma unroll
            for (int r = 0; r < 20; ++r) {
                float4 sv = sp[r*SPS];
                float hr = bx[r]*sv.x + by[r]*sv.y + bz[r]*sv.z;
                if (r < 5) run += hr;
                else       run += hr - ring[r % 5];
                ring[r % 5] = hr;
                if (r >= 4) myv[(r-4)*20] = run;
            }
        }
        __syncthreads();
        // pass 2: horizontal box sums, in-place (read 5 b128, write 4 b128)
        if (p2act && (ob + p2o) < oend) {
            float4 A = *(const float4*)(p2row);
            float4 B = *(const float4*)(p2row + 4);
            float4 Cv = *(const float4*)(p2row + 8);
            float4 Dv = *(const float4*)(p2row + 12);
            float4 Ev = *(const float4*)(p2row + 16);
            float v0=A.x,v1=A.y,v2=A.z,v3=A.w,v4=B.x,v5=B.y,v6=B.z,v7=B.w;
            float v8=Cv.x,v9=Cv.y,v10=Cv.z,v11=Cv.w,v12=Dv.x,v13=Dv.y,v14=Dv.z,v15=Dv.w;
            float v16=Ev.x,v17=Ev.y,v18=Ev.z,v19=Ev.w;
            float r0 = v0+v1+v2+v3+v4;
            float r1 = r0 + v5 - v0;
            float r2 = r1 + v6 - v1;
            float r3 = r2 + v7 - v2;
            float r4 = r3 + v8 - v3;
            float r5 = r4 + v9 - v4;
            float r6 = r5 + v10 - v5;
            float r7 = r6 + v11 - v6;
            float r8 = r7 + v12 - v7;
            float r9 = r8 + v13 - v8;
            float r10 = r9 + v14 - v9;
            float r11 = r10 + v15 - v10;
            float r12 = r11 + v16 - v11;
            float r13 = r12 + v17 - v12;
            float r14 = r13 + v18 - v13;
            float r15 = r14 + v19 - v14;
            *(float4*)(p2row)      = make_float4(r0, r1, r2, r3);
            *(float4*)(p2row + 4)  = make_float4(r4, r5, r6, r7);
            *(float4*)(p2row + 8)  = make_float4(r8, r9, r10, r11);
            *(float4*)(p2row + 12) = make_float4(r12, r13, r14, r15);
        }
        __syncthreads();
        // pass 3: distance + key insert (1 V read + 1 sS read per offset)
        for (int g = 0; g < OB; ++g) {
            int o2 = ob + g;
            if (o2 >= oend) break;
            u32 oy2 = (u32)o2 / 15u, ox2 = (u32)o2 - oy2*15u;
            float V = vb[g*CSOG];
            float d = fmaxf(Sbase + sS[(ty + (int)oy2)*SSS + (tx + (int)ox2)] - 2.f*V, 0.f);
            u32 key = (__float_as_uint(d) & 0xFFFFFF00u) | (u32)o2;
            if (key < kb[K_-1]) {
                kb[K_-1] = key;
                #pragma unroll
                for (int k = K_-1; k > 0; --k) {
                    if (kb[k] < kb[k-1]) { u32 tk = kb[k]; kb[k] = kb[k-1]; kb[k-1] = tk; }
                }
            }
        }
        __syncthreads();
    }

    int px = ((t*H_ + i0 + ty)*W_ + j0 + tx);
    uint4* pk = pkey + ((size_t)q*NPIX + px)*4;
    pk[0] = make_uint4(kb[0],  kb[1],  kb[2],  kb[3]);
    pk[1] = make_uint4(kb[4],  kb[5],  kb[6],  kb[7]);
    pk[2] = make_uint4(kb[8],  kb[9],  kb[10], kb[11]);
    pk[3] = make_uint4(kb[12], kb[13], 0xFFFFFFFFu, 0xFFFFFFFFu);
}

// ---------------- Kernel 4: fused merge + softmax + gather-aggregate ----------------
// output padded coord y = i + PW_; contributing queries qi = y - a, a in [0,5)
__global__ __launch_bounds__(256) void agg_kernel(const float4* __restrict__ P4,
                                                  const uint4* __restrict__ pkey,
                                                  const float* __restrict__ sigma,
                                                  const float* __restrict__ means,
                                                  float* __restrict__ out) {
    __shared__ float4 sPg[APR*APS];
    __shared__ float  sWt[AWR*AWR*AWS];
    __shared__ uint4  sIx[AWR*AWR];

    const int tid = threadIdx.x;
    const int part = tid & 3;
    const int lp = tid >> 2;                  // 0..63 local pixel
    const int tx = lp & 7, ty = lp >> 3;
    const int i0 = blockIdx.y * AT, j0 = blockIdx.x * AT;
    const int t = blockIdx.z;
    const float4* Pt = P4 + (size_t)t*(HP_*HP_);

    for (int e = tid; e < APR*APR; e += 256) {
        int r = e / APR, c = e % APR;
        sPg[r*APS + c] = Pt[(i0 + 2 + r)*HP_ + (j0 + 2 + c)];
    }

    // merge phase: one thread per staged neighbor (qi = i0 - 2 + r)
    if (tid < AWR*AWR) {
        int r = tid / AWR, c = tid - r*AWR;
        int qi = i0 - 2 + r, qj = j0 - 2 + c;
        if (qi >= 0 && qi < H_ && qj >= 0 && qj < W_) {
            size_t px = ((size_t)t*H_ + qi)*W_ + qj;
            u32 kb[K_];
            {
                const uint4* pk = pkey + px*4;
                uint4 a0=pk[0], a1=pk[1], a2=pk[2], a3=pk[3];
                kb[0]=a0.x; kb[1]=a0.y; kb[2]=a0.z; kb[3]=a0.w;
                kb[4]=a1.x; kb[5]=a1.y; kb[6]=a1.z; kb[7]=a1.w;
                kb[8]=a2.x; kb[9]=a2.y; kb[10]=a2.z; kb[11]=a2.w;
                kb[12]=a3.x; kb[13]=a3.y;
            }
            {
                const uint4* pk = pkey + ((size_t)NPIX + px)*4;
                uint4 b0=pk[0], b1=pk[1], b2=pk[2], b3=pk[3];
                u32 cand[K_] = {b0.x,b0.y,b0.z,b0.w, b1.x,b1.y,b1.z,b1.w,
                                b2.x,b2.y,b2.z,b2.w, b3.x,b3.y};
                #pragma unroll
                for (int k = 0; k < K_; ++k) {
                    u32 cd = cand[k];
                    if (cd >= kb[K_-1]) break;      // candidates sorted ascending
                    kb[K_-1] = cd;
                    #pragma unroll
                    for (int j = K_-1; j > 0; --j) {
                        if (kb[j] < kb[j-1]) { u32 tk = kb[j]; kb[j] = kb[j-1]; kb[j-1] = tk; }
                    }
                }
            }
            float sig = sigma[0] * (1.0f/255.0f) * 2.0f;
            float denom = 2.0f * (float)(C_*PS_*PS_) * (sig*sig) + 1e-8f;
            float d0 = __uint_as_float(kb[0] & 0xFFFFFF00u);
            float w[K_]; float sum = 0.f;
            #pragma unroll
            for (int k = 0; k < K_; ++k) {
                float d = __uint_as_float(kb[k] & 0xFFFFFF00u);
                w[k] = expf(-(d - d0) / denom); sum += w[k];
            }
            float inv = 1.0f / sum;
            float4* dst = (float4*)&sWt[tid*AWS];
            dst[0] = make_float4(w[0]*inv,  w[1]*inv,  w[2]*inv,  w[3]*inv);
            dst[1] = make_float4(w[4]*inv,  w[5]*inv,  w[6]*inv,  w[7]*inv);
            dst[2] = make_float4(w[8]*inv,  w[9]*inv,  w[10]*inv, w[11]*inv);
            dst[3] = make_float4(w[12]*inv, w[13]*inv, 0.f, 0.f);
            uint4 iv;
            iv.x = (kb[0]&255u)  | ((kb[1]&255u)<<8)  | ((kb[2]&255u)<<16)  | ((kb[3]&255u)<<24);
            iv.y = (kb[4]&255u)  | ((kb[5]&255u)<<8)  | ((kb[6]&255u)<<16)  | ((kb[7]&255u)<<24);
            iv.z = (kb[8]&255u)  | ((kb[9]&255u)<<8)  | ((kb[10]&255u)<<16) | ((kb[11]&255u)<<24);
            iv.w = (kb[12]&255u) | ((kb[13]&255u)<<8);
            sIx[tid] = iv;
        }
    }
    __syncthreads();

    const int i = i0 + ty, j = j0 + tx;
    float s0 = 0.f, s1 = 0.f, s2 = 0.f, cnt = 0.f;
    for (int ab = part; ab < 25; ab += 4) {
        int a = ab / 5, b = ab % 5;
        int qi = i + PW_ - a, qj = j + PW_ - b;
        if (qi < 0 || qi >= H_ || qj < 0 || qj >= W_) continue;
        cnt += 1.f;
        int le = (ty + 4 - a)*AWR + (tx + 4 - b);   // (qi - (i0-2)) = ty + 4 - a
        const float4* wv = (const float4*)&sWt[le*AWS];
        float4 wa = wv[0], wb = wv[1], wc = wv[2], wd = wv[3];
        uint4 ip = sIx[le];
        #define ACC(wval, obits) { \
            u32 o_ = (obits); \
            u32 oy_ = o_ / 15u; u32 ox_ = o_ - oy_*15u; \
            float4 v_ = sPg[(ty + (int)oy_)*APS + tx + (int)ox_]; \
            float w_ = (wval); \
            s0 += w_ * v_.x; s1 += w_ * v_.y; s2 += w_ * v_.z; }
        ACC(wa.x, ip.x & 255u);       ACC(wa.y, (ip.x>>8) & 255u);
        ACC(wa.z, (ip.x>>16) & 255u); ACC(wa.w, ip.x>>24);
        ACC(wb.x, ip.y & 255u);       ACC(wb.y, (ip.y>>8) & 255u);
        ACC(wb.z, (ip.y>>16) & 255u); ACC(wb.w, ip.y>>24);
        ACC(wc.x, ip.z & 255u);       ACC(wc.y, (ip.z>>8) & 255u);
        ACC(wc.z, (ip.z>>16) & 255u); ACC(wc.w, ip.z>>24);
        ACC(wd.x, ip.w & 255u);       ACC(wd.y, (ip.w>>8) & 255u);
        #undef ACC
    }

    s0 += __shfl_xor(s0, 1, 64); s0 += __shfl_xor(s0, 2, 64);
    s1 += __shfl_xor(s1, 1, 64); s1 += __shfl_xor(s1, 2, 64);
    s2 += __shfl_xor(s2, 1, 64); s2 += __shfl_xor(s2, 2, 64);
    cnt += __shfl_xor(cnt, 1, 64); cnt += __shfl_xor(cnt, 2, 64);

    if (part == 0) {
        float invc = 1.0f / (cnt + 1e-10f);
        float m0 = means[t*3+0], m1 = means[t*3+1], m2 = means[t*3+2];
        size_t obase = (size_t)t*(C_*H_*W_) + (size_t)i*W_ + j;
        out[obase]             = 127.5f * (s0*invc + m0 + 1.0f);
        out[obase +   H_*W_]   = 127.5f * (s1*invc + m1 + 1.0f);
        out[obase + 2*(H_*W_)] = 127.5f * (s2*invc + m2 + 1.0f);
    }
}

extern "C" void kernel_launch(void* const* d_in, const int* in_sizes, int n_in,
                              void* d_out, int out_size, void* d_ws, size_t ws_size,
                              hipStream_t stream) {
    const float* noisy = (const float*)d_in[0];
    const float* sigma = (const float*)d_in[1];
    float* out = (float*)d_out;
    float* ws  = (float*)d_ws;

    // ws layout (float offsets, all 16B aligned):
    float*  means = ws;                          // 16
    float4* P4    = (float4*)(ws + 16);          // 341056 floats
    uint4*  pkey  = (uint4*)(ws + 16 + 341056);  // 2*NPIX*16 u32 = 2097152
    // total ~2.44M floats ~ 9.8 MB

    hipLaunchKernelGGL(means_kernel, dim3(T_*C_), dim3(256), 0, stream, noisy, means);

    int padN = T_*HP_*HP_;
    hipLaunchKernelGGL(pad4_kernel, dim3((padN + 255)/256), dim3(256), 0, stream,
                       noisy, means, P4);

    hipLaunchKernelGGL(fused_topk, dim3(W_/TILE, H_/TILE, T_*NQ), dim3(256), 0, stream,
                       P4, pkey);

    hipLaunchKernelGGL(agg_kernel, dim3(W_/AT, H_/AT, T_), dim3(256), 0, stream,
                       P4, pkey, sigma, means, out);
}